// Round 4
// baseline (175.876 us; speedup 1.0000x reference)
//
#include <hip/hip_runtime.h>

#define BB 4
#define CCH 384
#define HH 56
#define WWD 56
#define HW 3136
#define S2 49
#define S2P 52
#define D2 192
#define K2 25
#define XSP 20          // xs leading dim

// ---- Kernel 1: GTt[i][j] = sum_d A[d][i] * B[d][j]   (384x384, K=192) ----
// Called as gt_k(Wq, Wk, GT): produces GTt[t][i] = sum_d Wq[d][t] Wk[d][i],
// so mv threads read contiguous rows.
__global__ __launch_bounds__(256) void gt_k(const float* __restrict__ Wk,
                                            const float* __restrict__ Wq,
                                            float* __restrict__ GT) {
    __shared__ float As[D2 * 16];
    __shared__ float Bs[D2 * 16];
    int bi = blockIdx.x % 24, bj = blockIdx.x / 24;
    int t = threadIdx.x;
    int tj = t & 15, ti = t >> 4;
#pragma unroll
    for (int k = 0; k < 3; k++) {
        int idx = t + 256 * k;
        int d = idx >> 2, q = idx & 3;
        *(float4*)&As[idx * 4] = *(const float4*)&Wk[(size_t)d * CCH + bi * 16 + 4 * q];
        *(float4*)&Bs[idx * 4] = *(const float4*)&Wq[(size_t)d * CCH + bj * 16 + 4 * q];
    }
    __syncthreads();
    float acc = 0.f;
#pragma unroll 8
    for (int d = 0; d < D2; d++)
        acc += As[d * 16 + ti] * Bs[d * 16 + tj];
    GT[(size_t)(bi * 16 + ti) * CCH + bj * 16 + tj] = acc;
}

// ---- Kernel 2: one block per s (49 blocks): pool all 4 batches' bins,
// then each thread reads its GT row ONCE and serves all 4 batches.
// GT L2-demand: 49 x 576KB = 28 MB (was 196 x 576KB = 113 MB); ~6 blocks/XCD
// keeps GT resident per XCD-L2 under the poison drain.
__global__ __launch_bounds__(384) void smv_k(const float* __restrict__ ctx,
                                             const float* __restrict__ GTt,
                                             float* __restrict__ M) {
    __shared__ float v4[4][CCH];
    int s = blockIdx.x;
    int t = threadIdx.x;
    int sy = s / 7, sx = s % 7;
    // Phase 1: pooling, 4 batches (64 independent float4 loads -> good MLP)
#pragma unroll
    for (int b = 0; b < 4; b++) {
        const float* p = ctx + ((size_t)(b * CCH + t)) * HW + sy * 8 * WWD + sx * 8;
        float sum = 0.f;
#pragma unroll
        for (int r = 0; r < 8; r++) {
            float4 a = *(const float4*)(p + r * WWD);
            float4 c = *(const float4*)(p + r * WWD + 4);
            sum += a.x + a.y + a.z + a.w + c.x + c.y + c.z + c.w;
        }
        v4[b][t] = sum * (1.f / 64.f);
    }
    __syncthreads();
    // Phase 2: GT row t read once, 4 batch accumulators (4 chains)
    const float4* g4 = (const float4*)(GTt + (size_t)t * CCH);
    float acc0 = 0.f, acc1 = 0.f, acc2 = 0.f, acc3 = 0.f;
#pragma unroll 8
    for (int i = 0; i < CCH / 4; i++) {
        float4 gv = g4[i];
        float4 q0 = *(const float4*)&v4[0][4 * i];   // uniform addr -> broadcast
        float4 q1 = *(const float4*)&v4[1][4 * i];
        float4 q2 = *(const float4*)&v4[2][4 * i];
        float4 q3 = *(const float4*)&v4[3][4 * i];
        acc0 += gv.x * q0.x + gv.y * q0.y + gv.z * q0.z + gv.w * q0.w;
        acc1 += gv.x * q1.x + gv.y * q1.y + gv.z * q1.z + gv.w * q1.w;
        acc2 += gv.x * q2.x + gv.y * q2.y + gv.z * q2.z + gv.w * q2.w;
        acc3 += gv.x * q3.x + gv.y * q3.y + gv.z * q3.z + gv.w * q3.w;
    }
    M[((size_t)(0 * CCH + t)) * S2P + s] = acc0;
    M[((size_t)(1 * CCH + t)) * S2P + s] = acc1;
    M[((size_t)(2 * CCH + t)) * S2P + s] = acc2;
    M[((size_t)(3 * CCH + t)) * S2P + s] = acc3;
    if (s < 3) {
#pragma unroll
        for (int b = 0; b < 4; b++)
            M[((size_t)(b * CCH + t)) * S2P + 49 + s] = 0.f;
    }
}

// ---- Kernel 3: scores = x^T M (16-way K-split), softmax(49), dyn = Wwd*A ----
// (unchanged)
__global__ __launch_bounds__(256) void attn_k(const float* __restrict__ x,
                                              const float* __restrict__ M,
                                              const float* __restrict__ Wwd,
                                              float* __restrict__ dyn) {
    __shared__ __align__(16) float smem[96 * XSP + 96 * S2P];  // xs | Ms ; red aliases
    __shared__ __align__(16) float sc[16 * S2P];
    __shared__ __align__(16) float wl[K2 * S2P];
    float* xs  = smem;               // [96][20]
    float* Ms  = smem + 96 * XSP;    // [96][52]
    float* red = smem;               // [4][16][52] = 3328 floats, aliases xs+Ms head

    int b  = blockIdx.x / 196;
    int n0 = (blockIdx.x % 196) * 16;
    int t  = threadIdx.x;
    int pxg = t & 3, sg = (t >> 2) & 3, slice = t >> 4;

    float4 acc4[4][4];
#pragma unroll
    for (int k = 0; k < 4; k++)
#pragma unroll
        for (int j = 0; j < 4; j++) acc4[k][j] = make_float4(0.f, 0.f, 0.f, 0.f);

    const float* xb = x + (size_t)b * CCH * HW + n0;
    const float* Mb = M + (size_t)b * CCH * S2P;

    // hoisted Wwd staging
#pragma unroll
    for (int k = 0; k < 5; k++) {
        int i = t + 256 * k;
        int j = i / S2P, ss = i - j * S2P;
        wl[i] = (ss < S2) ? Wwd[j * S2 + ss] : 0.f;
    }
    if (t < 20) {
        int i = t + 1280;
        int j = i / S2P, ss = i - j * S2P;
        wl[i] = (ss < S2) ? Wwd[j * S2 + ss] : 0.f;
    }

    int r0 = t >> 2, cq = t & 3;
    int r1 = (t + 256) >> 2;            // (t+256)&3 == t&3
    float4 px0, px1, pm0, pm1, pm2, pm3, pm4;

#define ATTN_LOAD(c0)                                                          \
    {                                                                          \
        px0 = *(const float4*)&xb[(size_t)((c0) + r0) * HW + 4 * cq];          \
        if (t < 128)                                                           \
            px1 = *(const float4*)&xb[(size_t)((c0) + r1) * HW + 4 * cq];      \
        const float* srcm = Mb + (size_t)(c0) * S2P;                           \
        pm0 = *(const float4*)&srcm[4 * t];                                    \
        pm1 = *(const float4*)&srcm[4 * (t + 256)];                            \
        pm2 = *(const float4*)&srcm[4 * (t + 512)];                            \
        pm3 = *(const float4*)&srcm[4 * (t + 768)];                            \
        if (t < 224) pm4 = *(const float4*)&srcm[4 * (t + 1024)];              \
    }

#define ATTN_WRITE()                                                           \
    {                                                                          \
        *(float4*)&xs[r0 * XSP + 4 * cq] = px0;                                \
        if (t < 128) *(float4*)&xs[r1 * XSP + 4 * cq] = px1;                   \
        *(float4*)&Ms[4 * t] = pm0;                                            \
        *(float4*)&Ms[4 * (t + 256)] = pm1;                                    \
        *(float4*)&Ms[4 * (t + 512)] = pm2;                                    \
        *(float4*)&Ms[4 * (t + 768)] = pm3;                                    \
        if (t < 224) *(float4*)&Ms[4 * (t + 1024)] = pm4;                      \
    }

    ATTN_LOAD(0);
    for (int ch = 0; ch < 4; ch++) {
        ATTN_WRITE();
        __syncthreads();
        if (ch < 3) { ATTN_LOAD((ch + 1) * 96); }
        int rbase = 6 * slice;
#pragma unroll
        for (int m = 0; m < 6; m++) {
            int r = rbase + m;
            const float4 xv = *(const float4*)&xs[r * XSP + 4 * pxg];
#pragma unroll
            for (int k = 0; k < 3; k++) {
                int g = sg + 4 * k;
                const float4 mv = *(const float4*)&Ms[r * S2P + 4 * g];
                acc4[k][0].x += mv.x * xv.x; acc4[k][0].y += mv.x * xv.y;
                acc4[k][0].z += mv.x * xv.z; acc4[k][0].w += mv.x * xv.w;
                acc4[k][1].x += mv.y * xv.x; acc4[k][1].y += mv.y * xv.y;
                acc4[k][1].z += mv.y * xv.z; acc4[k][1].w += mv.y * xv.w;
                acc4[k][2].x += mv.z * xv.x; acc4[k][2].y += mv.z * xv.y;
                acc4[k][2].z += mv.z * xv.z; acc4[k][2].w += mv.z * xv.w;
                acc4[k][3].x += mv.w * xv.x; acc4[k][3].y += mv.w * xv.y;
                acc4[k][3].z += mv.w * xv.z; acc4[k][3].w += mv.w * xv.w;
            }
            if (sg == 0) {
                const float4 mv = *(const float4*)&Ms[r * S2P + 48];
                acc4[3][0].x += mv.x * xv.x; acc4[3][0].y += mv.x * xv.y;
                acc4[3][0].z += mv.x * xv.z; acc4[3][0].w += mv.x * xv.w;
                acc4[3][1].x += mv.y * xv.x; acc4[3][1].y += mv.y * xv.y;
                acc4[3][1].z += mv.y * xv.z; acc4[3][1].w += mv.y * xv.w;
                acc4[3][2].x += mv.z * xv.x; acc4[3][2].y += mv.z * xv.y;
                acc4[3][2].z += mv.z * xv.z; acc4[3][2].w += mv.z * xv.w;
                acc4[3][3].x += mv.w * xv.x; acc4[3][3].y += mv.w * xv.y;
                acc4[3][3].z += mv.w * xv.z; acc4[3][3].w += mv.w * xv.w;
            }
        }
        __syncthreads();
    }

    // in-wave reduce across 4 slice-groups (lane^16, lane^32)
#pragma unroll
    for (int k = 0; k < 4; k++)
#pragma unroll
        for (int j = 0; j < 4; j++) {
            acc4[k][j].x += __shfl_xor(acc4[k][j].x, 16);
            acc4[k][j].y += __shfl_xor(acc4[k][j].y, 16);
            acc4[k][j].z += __shfl_xor(acc4[k][j].z, 16);
            acc4[k][j].w += __shfl_xor(acc4[k][j].w, 16);
            acc4[k][j].x += __shfl_xor(acc4[k][j].x, 32);
            acc4[k][j].y += __shfl_xor(acc4[k][j].y, 32);
            acc4[k][j].z += __shfl_xor(acc4[k][j].z, 32);
            acc4[k][j].w += __shfl_xor(acc4[k][j].w, 32);
        }

    // wave partials -> red[wave][16px][52]
    if ((t & 63) < 16) {
        int wv = t >> 6;
        float* rb = red + (size_t)wv * 16 * S2P;
#pragma unroll
        for (int k = 0; k < 4; k++) {
            int g = sg + 4 * k;
            if (g < 13) {
                *(float4*)&rb[(4 * pxg + 0) * S2P + 4 * g] =
                    make_float4(acc4[k][0].x, acc4[k][1].x, acc4[k][2].x, acc4[k][3].x);
                *(float4*)&rb[(4 * pxg + 1) * S2P + 4 * g] =
                    make_float4(acc4[k][0].y, acc4[k][1].y, acc4[k][2].y, acc4[k][3].y);
                *(float4*)&rb[(4 * pxg + 2) * S2P + 4 * g] =
                    make_float4(acc4[k][0].z, acc4[k][1].z, acc4[k][2].z, acc4[k][3].z);
                *(float4*)&rb[(4 * pxg + 3) * S2P + 4 * g] =
                    make_float4(acc4[k][0].w, acc4[k][1].w, acc4[k][2].w, acc4[k][3].w);
            }
        }
    }
    __syncthreads();

    // final reduce over 4 waves -> sc
    if (t < 208) {
        int px = t / 13, q = t - px * 13;
        float4 ssum = make_float4(0.f, 0.f, 0.f, 0.f);
#pragma unroll
        for (int wv = 0; wv < 4; wv++) {
            float4 vv = *(float4*)&red[(size_t)(wv * 16 + px) * S2P + 4 * q];
            ssum.x += vv.x; ssum.y += vv.y; ssum.z += vv.z; ssum.w += vv.w;
        }
        *(float4*)&sc[px * S2P + 4 * q] = ssum;
    }
    __syncthreads();

    // softmax (threads < 128: 8 lanes per pixel); wl already staged
    if (t < 128) {
        int px = t >> 3, li = t & 7;
        float mx = -3.4e38f;
#pragma unroll
        for (int k = 0; k < 7; k++) { int s = li + 8 * k; if (s < S2) mx = fmaxf(mx, sc[px * S2P + s]); }
        mx = fmaxf(mx, __shfl_xor(mx, 1, 8));
        mx = fmaxf(mx, __shfl_xor(mx, 2, 8));
        mx = fmaxf(mx, __shfl_xor(mx, 4, 8));
        float e[7]; float sum = 0.f;
#pragma unroll
        for (int k = 0; k < 7; k++) {
            int s = li + 8 * k;
            if (s < S2) { e[k] = __expf(sc[px * S2P + s] - mx); sum += e[k]; }
        }
        sum += __shfl_xor(sum, 1, 8);
        sum += __shfl_xor(sum, 2, 8);
        sum += __shfl_xor(sum, 4, 8);
        float inv = 1.f / sum;
#pragma unroll
        for (int k = 0; k < 7; k++) {
            int s = li + 8 * k;
            if (s < S2) sc[px * S2P + s] = e[k] * inv;
        }
    }
    __syncthreads();

    // dyn[b,j,n0+px] = sum_s wl[j,s]*sc[px,s]   (400 outs: 256 + 144)
    float* dynb = dyn + (size_t)b * K2 * HW + n0;
#pragma unroll
    for (int pass = 0; pass < 2; pass++) {
        int o = t + 256 * pass;
        if (pass == 0 || t < 144) {
            int j = o >> 4, px = o & 15;
            float a = 0.f;
#pragma unroll
            for (int q = 0; q < 13; q++) {
                float4 wv = *(float4*)&wl[j * S2P + 4 * q];
                float4 pv = *(float4*)&sc[px * S2P + 4 * q];
                a += wv.x * pv.x + wv.y * pv.y + wv.z * pv.z + wv.w * pv.w;
            }
            dynb[(size_t)j * HW + px] = a;
        }
    }
#undef ATTN_LOAD
#undef ATTN_WRITE
}

// ---- Kernel 4: 5x5 dynamic stencil; 16 ch x 8-row stripe; 2 rows/thread ----
__global__ __launch_bounds__(256, 3) void out_k(const float* __restrict__ x,
                                                const float* __restrict__ dyn,
                                                float* __restrict__ out) {
    __shared__ float xt[16][12][60];
    int blk    = blockIdx.x;
    int stripe = blk % 7;
    int cg     = (blk / 7) % 24;
    int b      = blk / (7 * 24);
    int h0 = stripe * 8;
    int c0 = cg * 16;
    int t  = threadIdx.x;
    const float* xb = x + ((size_t)(b * CCH + c0)) * HW;

    if (t < 192) {
        int cc = t / 12, r = t % 12;
        xt[cc][r][0] = 0.f; xt[cc][r][1] = 0.f;
        xt[cc][r][58] = 0.f; xt[cc][r][59] = 0.f;
    }
#pragma unroll
    for (int k = 0; k < 11; k++) {
        int idx = t + 256 * k;
        if (k < 10 || t < 128) {
            int cc  = idx / 168;
            int rem = idx - cc * 168;
            int r   = rem / 14;
            int q   = rem - r * 14;
            int h   = h0 - 2 + r;
            float4 v = make_float4(0.f, 0.f, 0.f, 0.f);
            if ((unsigned)h < (unsigned)HH)
                v = *(const float4*)&xb[(size_t)cc * HW + h * WWD + 4 * q];
            xt[cc][r][2 + 4 * q + 0] = v.x;
            xt[cc][r][2 + 4 * q + 1] = v.y;
            xt[cc][r][2 + 4 * q + 2] = v.z;
            xt[cc][r][2 + 4 * q + 3] = v.w;
        }
    }

    bool act = t < 224;
    int w = t % 56;
    int u = t / 56;                  // 0..3 -> rows 2u, 2u+1
    int n = (h0 + 2 * u) * WWD + w;
    float dv0[K2], dv1[K2];
    if (act) {
        const float* db = dyn + (size_t)b * K2 * HW + n;
#pragma unroll
        for (int j = 0; j < K2; j++) {
            dv0[j] = db[(size_t)j * HW];
            dv1[j] = db[(size_t)j * HW + WWD];
        }
    }
    __syncthreads();
    if (!act) return;

    float* ob = out + ((size_t)(b * CCH + c0)) * HW + n;
#pragma unroll
    for (int cc = 0; cc < 16; cc++) {
        float a0 = 0.f, a1 = 0.f;
#pragma unroll
        for (int rr = 0; rr < 6; rr++) {
            int lr = 2 * u + rr;
            float v0 = xt[cc][lr][w + 0];
            float v1 = xt[cc][lr][w + 1];
            float v2 = xt[cc][lr][w + 2];
            float v3 = xt[cc][lr][w + 3];
            float v4 = xt[cc][lr][w + 4];
            if (rr < 5) {
                int o5 = rr * 5;
                a0 += v0 * dv0[o5] + v1 * dv0[o5 + 1] + v2 * dv0[o5 + 2]
                    + v3 * dv0[o5 + 3] + v4 * dv0[o5 + 4];
            }
            if (rr >= 1) {
                int o5 = (rr - 1) * 5;
                a1 += v0 * dv1[o5] + v1 * dv1[o5 + 1] + v2 * dv1[o5 + 2]
                    + v3 * dv1[o5 + 3] + v4 * dv1[o5 + 4];
            }
        }
        ob[(size_t)cc * HW] = a0;
        ob[(size_t)cc * HW + WWD] = a1;
    }
}

extern "C" void kernel_launch(void* const* d_in, const int* in_sizes, int n_in,
                              void* d_out, int out_size, void* d_ws, size_t ws_size,
                              hipStream_t stream) {
    const float* x   = (const float*)d_in[0];
    const float* ctx = (const float*)d_in[1];
    const float* Wq  = (const float*)d_in[2];
    const float* Wk  = (const float*)d_in[3];
    const float* Wwd = (const float*)d_in[4];
    float* out = (float*)d_out;
    float* ws  = (float*)d_ws;

    float* GT  = ws;                    // 384*384            = 147456  (GT transposed)
    float* M   = ws + 147456;           // B*384*52           =  79872
    float* dyn = ws + 147456 + 79872;   // B*25*3136          = 313600

    // NOTE swapped args: produces GTt[t][i] = sum_d Wq[d][t] Wk[d][i]
    gt_k<<<24 * 24, 256, 0, stream>>>(Wq, Wk, GT);
    smv_k<<<S2, 384, 0, stream>>>(ctx, GT, M);
    attn_k<<<BB * 196, 256, 0, stream>>>(x, M, Wwd, dyn);
    out_k<<<BB * 24 * 7, 256, 0, stream>>>(x, dyn, out);
}

// Round 5
// 168.514 us; speedup vs baseline: 1.0437x; 1.0437x over previous
//
#include <hip/hip_runtime.h>

#define BB 4
#define CCH 384
#define HH 56
#define WWD 56
#define HW 3136
#define S2 49
#define S2P 52
#define D2 192
#define K2 25
#define XSP 20          // xs leading dim

// ---- Kernel 1: GTt[i][j] = sum_d A[d][i] * B[d][j]   (384x384, K=192) ----
// Called as gt_k(Wq, Wk, GT): produces GTt[t][i] = sum_d Wq[d][t] Wk[d][i].
__global__ __launch_bounds__(256) void gt_k(const float* __restrict__ Wk,
                                            const float* __restrict__ Wq,
                                            float* __restrict__ GT) {
    __shared__ float As[D2 * 16];
    __shared__ float Bs[D2 * 16];
    int bi = blockIdx.x % 24, bj = blockIdx.x / 24;
    int t = threadIdx.x;
    int tj = t & 15, ti = t >> 4;
#pragma unroll
    for (int k = 0; k < 3; k++) {
        int idx = t + 256 * k;
        int d = idx >> 2, q = idx & 3;
        *(float4*)&As[idx * 4] = *(const float4*)&Wk[(size_t)d * CCH + bi * 16 + 4 * q];
        *(float4*)&Bs[idx * 4] = *(const float4*)&Wq[(size_t)d * CCH + bj * 16 + 4 * q];
    }
    __syncthreads();
    float acc = 0.f;
#pragma unroll 8
    for (int d = 0; d < D2; d++)
        acc += As[d * 16 + ti] * Bs[d * 16 + tj];
    GT[(size_t)(bi * 16 + ti) * CCH + bj * 16 + tj] = acc;
}

// ---- Kernel 2a: pooling. 196 blocks (b,s); thread = channel. Streams the
// unavoidable 19.3 MB of ctx with full machine parallelism. ----
__global__ __launch_bounds__(384) void pool_k(const float* __restrict__ ctx,
                                              float* __restrict__ P) {
    int bs = blockIdx.x;                 // b*49 + s
    int b = bs / S2, s = bs - b * S2;
    int t = threadIdx.x;
    int sy = s / 7, sx = s % 7;
    const float* p = ctx + ((size_t)(b * CCH + t)) * HW + sy * 8 * WWD + sx * 8;
    float sum = 0.f;
#pragma unroll
    for (int r = 0; r < 8; r++) {
        float4 a  = *(const float4*)(p + r * WWD);
        float4 c4 = *(const float4*)(p + r * WWD + 4);
        sum += a.x + a.y + a.z + a.w + c4.x + c4.y + c4.z + c4.w;
    }
    P[(size_t)bs * CCH + t] = sum * (1.f / 64.f);
}

// ---- Kernel 2b: M[b,t,s] = GT row t . P[b*49+s]. 192 blocks x 256 thr.
// Each GT row is read by exactly ONE block (GT HBM demand = 576 KB total);
// within a wave all lanes read the same GT float4 (L1 broadcast). P (301 KB)
// is L2-resident. Two independent dot chains per thread. ----
__global__ __launch_bounds__(256) void mv2_k(const float* __restrict__ GTt,
                                             const float* __restrict__ P,
                                             float* __restrict__ M) {
    int t = threadIdx.x;
    int r = blockIdx.x * 2 + (t >> 7);   // GT row / output channel
    int c = t & 127;
    int bs0 = c, bs1 = c + 128;
    bool has1 = (bs1 < BB * S2);         // 196 columns
    const float4* g4 = (const float4*)(GTt + (size_t)r * CCH);
    const float4* p0 = (const float4*)(P + (size_t)bs0 * CCH);
    const float4* p1 = (const float4*)(P + (size_t)(has1 ? bs1 : bs0) * CCH);
    float a0 = 0.f, a1 = 0.f, a2 = 0.f, a3 = 0.f;
#pragma unroll 8
    for (int i = 0; i < CCH / 4; i++) {
        float4 g  = g4[i];
        float4 q0 = p0[i];
        float4 q1 = p1[i];
        a0 += g.x * q0.x + g.y * q0.y;
        a1 += g.z * q0.z + g.w * q0.w;
        a2 += g.x * q1.x + g.y * q1.y;
        a3 += g.z * q1.z + g.w * q1.w;
    }
    int b0 = bs0 / S2, s0 = bs0 - b0 * S2;
    M[((size_t)(b0 * CCH + r)) * S2P + s0] = a0 + a1;
    if (has1) {
        int b1 = bs1 / S2, s1 = bs1 - b1 * S2;
        M[((size_t)(b1 * CCH + r)) * S2P + s1] = a2 + a3;
    }
    if (c >= 68 && c < 80) {             // zero the 3-col pad for each batch
        int rem = c - 68;                // 0..11
        int bb = rem / 3, sp = 49 + rem % 3;
        M[((size_t)(bb * CCH + r)) * S2P + sp] = 0.f;
    }
}

// ---- Kernel 3: scores = x^T M (16-way K-split), softmax(49), dyn = Wwd*A ----
// (unchanged)
__global__ __launch_bounds__(256) void attn_k(const float* __restrict__ x,
                                              const float* __restrict__ M,
                                              const float* __restrict__ Wwd,
                                              float* __restrict__ dyn) {
    __shared__ __align__(16) float smem[96 * XSP + 96 * S2P];  // xs | Ms ; red aliases
    __shared__ __align__(16) float sc[16 * S2P];
    __shared__ __align__(16) float wl[K2 * S2P];
    float* xs  = smem;               // [96][20]
    float* Ms  = smem + 96 * XSP;    // [96][52]
    float* red = smem;               // [4][16][52] = 3328 floats, aliases xs+Ms head

    int b  = blockIdx.x / 196;
    int n0 = (blockIdx.x % 196) * 16;
    int t  = threadIdx.x;
    int pxg = t & 3, sg = (t >> 2) & 3, slice = t >> 4;

    float4 acc4[4][4];
#pragma unroll
    for (int k = 0; k < 4; k++)
#pragma unroll
        for (int j = 0; j < 4; j++) acc4[k][j] = make_float4(0.f, 0.f, 0.f, 0.f);

    const float* xb = x + (size_t)b * CCH * HW + n0;
    const float* Mb = M + (size_t)b * CCH * S2P;

    // hoisted Wwd staging
#pragma unroll
    for (int k = 0; k < 5; k++) {
        int i = t + 256 * k;
        int j = i / S2P, ss = i - j * S2P;
        wl[i] = (ss < S2) ? Wwd[j * S2 + ss] : 0.f;
    }
    if (t < 20) {
        int i = t + 1280;
        int j = i / S2P, ss = i - j * S2P;
        wl[i] = (ss < S2) ? Wwd[j * S2 + ss] : 0.f;
    }

    int r0 = t >> 2, cq = t & 3;
    int r1 = (t + 256) >> 2;            // (t+256)&3 == t&3
    float4 px0, px1, pm0, pm1, pm2, pm3, pm4;

#define ATTN_LOAD(c0)                                                          \
    {                                                                          \
        px0 = *(const float4*)&xb[(size_t)((c0) + r0) * HW + 4 * cq];          \
        if (t < 128)                                                           \
            px1 = *(const float4*)&xb[(size_t)((c0) + r1) * HW + 4 * cq];      \
        const float* srcm = Mb + (size_t)(c0) * S2P;                           \
        pm0 = *(const float4*)&srcm[4 * t];                                    \
        pm1 = *(const float4*)&srcm[4 * (t + 256)];                            \
        pm2 = *(const float4*)&srcm[4 * (t + 512)];                            \
        pm3 = *(const float4*)&srcm[4 * (t + 768)];                            \
        if (t < 224) pm4 = *(const float4*)&srcm[4 * (t + 1024)];              \
    }

#define ATTN_WRITE()                                                           \
    {                                                                          \
        *(float4*)&xs[r0 * XSP + 4 * cq] = px0;                                \
        if (t < 128) *(float4*)&xs[r1 * XSP + 4 * cq] = px1;                   \
        *(float4*)&Ms[4 * t] = pm0;                                            \
        *(float4*)&Ms[4 * (t + 256)] = pm1;                                    \
        *(float4*)&Ms[4 * (t + 512)] = pm2;                                    \
        *(float4*)&Ms[4 * (t + 768)] = pm3;                                    \
        if (t < 224) *(float4*)&Ms[4 * (t + 1024)] = pm4;                      \
    }

    ATTN_LOAD(0);
    for (int ch = 0; ch < 4; ch++) {
        ATTN_WRITE();
        __syncthreads();
        if (ch < 3) { ATTN_LOAD((ch + 1) * 96); }
        int rbase = 6 * slice;
#pragma unroll
        for (int m = 0; m < 6; m++) {
            int r = rbase + m;
            const float4 xv = *(const float4*)&xs[r * XSP + 4 * pxg];
#pragma unroll
            for (int k = 0; k < 3; k++) {
                int g = sg + 4 * k;
                const float4 mv = *(const float4*)&Ms[r * S2P + 4 * g];
                acc4[k][0].x += mv.x * xv.x; acc4[k][0].y += mv.x * xv.y;
                acc4[k][0].z += mv.x * xv.z; acc4[k][0].w += mv.x * xv.w;
                acc4[k][1].x += mv.y * xv.x; acc4[k][1].y += mv.y * xv.y;
                acc4[k][1].z += mv.y * xv.z; acc4[k][1].w += mv.y * xv.w;
                acc4[k][2].x += mv.z * xv.x; acc4[k][2].y += mv.z * xv.y;
                acc4[k][2].z += mv.z * xv.z; acc4[k][2].w += mv.z * xv.w;
                acc4[k][3].x += mv.w * xv.x; acc4[k][3].y += mv.w * xv.y;
                acc4[k][3].z += mv.w * xv.z; acc4[k][3].w += mv.w * xv.w;
            }
            if (sg == 0) {
                const float4 mv = *(const float4*)&Ms[r * S2P + 48];
                acc4[3][0].x += mv.x * xv.x; acc4[3][0].y += mv.x * xv.y;
                acc4[3][0].z += mv.x * xv.z; acc4[3][0].w += mv.x * xv.w;
                acc4[3][1].x += mv.y * xv.x; acc4[3][1].y += mv.y * xv.y;
                acc4[3][1].z += mv.y * xv.z; acc4[3][1].w += mv.y * xv.w;
                acc4[3][2].x += mv.z * xv.x; acc4[3][2].y += mv.z * xv.y;
                acc4[3][2].z += mv.z * xv.z; acc4[3][2].w += mv.z * xv.w;
                acc4[3][3].x += mv.w * xv.x; acc4[3][3].y += mv.w * xv.y;
                acc4[3][3].z += mv.w * xv.z; acc4[3][3].w += mv.w * xv.w;
            }
        }
        __syncthreads();
    }

    // in-wave reduce across 4 slice-groups (lane^16, lane^32)
#pragma unroll
    for (int k = 0; k < 4; k++)
#pragma unroll
        for (int j = 0; j < 4; j++) {
            acc4[k][j].x += __shfl_xor(acc4[k][j].x, 16);
            acc4[k][j].y += __shfl_xor(acc4[k][j].y, 16);
            acc4[k][j].z += __shfl_xor(acc4[k][j].z, 16);
            acc4[k][j].w += __shfl_xor(acc4[k][j].w, 16);
            acc4[k][j].x += __shfl_xor(acc4[k][j].x, 32);
            acc4[k][j].y += __shfl_xor(acc4[k][j].y, 32);
            acc4[k][j].z += __shfl_xor(acc4[k][j].z, 32);
            acc4[k][j].w += __shfl_xor(acc4[k][j].w, 32);
        }

    // wave partials -> red[wave][16px][52]
    if ((t & 63) < 16) {
        int wv = t >> 6;
        float* rb = red + (size_t)wv * 16 * S2P;
#pragma unroll
        for (int k = 0; k < 4; k++) {
            int g = sg + 4 * k;
            if (g < 13) {
                *(float4*)&rb[(4 * pxg + 0) * S2P + 4 * g] =
                    make_float4(acc4[k][0].x, acc4[k][1].x, acc4[k][2].x, acc4[k][3].x);
                *(float4*)&rb[(4 * pxg + 1) * S2P + 4 * g] =
                    make_float4(acc4[k][0].y, acc4[k][1].y, acc4[k][2].y, acc4[k][3].y);
                *(float4*)&rb[(4 * pxg + 2) * S2P + 4 * g] =
                    make_float4(acc4[k][0].z, acc4[k][1].z, acc4[k][2].z, acc4[k][3].z);
                *(float4*)&rb[(4 * pxg + 3) * S2P + 4 * g] =
                    make_float4(acc4[k][0].w, acc4[k][1].w, acc4[k][2].w, acc4[k][3].w);
            }
        }
    }
    __syncthreads();

    // final reduce over 4 waves -> sc
    if (t < 208) {
        int px = t / 13, q = t - px * 13;
        float4 ssum = make_float4(0.f, 0.f, 0.f, 0.f);
#pragma unroll
        for (int wv = 0; wv < 4; wv++) {
            float4 vv = *(float4*)&red[(size_t)(wv * 16 + px) * S2P + 4 * q];
            ssum.x += vv.x; ssum.y += vv.y; ssum.z += vv.z; ssum.w += vv.w;
        }
        *(float4*)&sc[px * S2P + 4 * q] = ssum;
    }
    __syncthreads();

    // softmax (threads < 128: 8 lanes per pixel); wl already staged
    if (t < 128) {
        int px = t >> 3, li = t & 7;
        float mx = -3.4e38f;
#pragma unroll
        for (int k = 0; k < 7; k++) { int s = li + 8 * k; if (s < S2) mx = fmaxf(mx, sc[px * S2P + s]); }
        mx = fmaxf(mx, __shfl_xor(mx, 1, 8));
        mx = fmaxf(mx, __shfl_xor(mx, 2, 8));
        mx = fmaxf(mx, __shfl_xor(mx, 4, 8));
        float e[7]; float sum = 0.f;
#pragma unroll
        for (int k = 0; k < 7; k++) {
            int s = li + 8 * k;
            if (s < S2) { e[k] = __expf(sc[px * S2P + s] - mx); sum += e[k]; }
        }
        sum += __shfl_xor(sum, 1, 8);
        sum += __shfl_xor(sum, 2, 8);
        sum += __shfl_xor(sum, 4, 8);
        float inv = 1.f / sum;
#pragma unroll
        for (int k = 0; k < 7; k++) {
            int s = li + 8 * k;
            if (s < S2) sc[px * S2P + s] = e[k] * inv;
        }
    }
    __syncthreads();

    // dyn[b,j,n0+px] = sum_s wl[j,s]*sc[px,s]   (400 outs: 256 + 144)
    float* dynb = dyn + (size_t)b * K2 * HW + n0;
#pragma unroll
    for (int pass = 0; pass < 2; pass++) {
        int o = t + 256 * pass;
        if (pass == 0 || t < 144) {
            int j = o >> 4, px = o & 15;
            float a = 0.f;
#pragma unroll
            for (int q = 0; q < 13; q++) {
                float4 wv = *(float4*)&wl[j * S2P + 4 * q];
                float4 pv = *(float4*)&sc[px * S2P + 4 * q];
                a += wv.x * pv.x + wv.y * pv.y + wv.z * pv.z + wv.w * pv.w;
            }
            dynb[(size_t)j * HW + px] = a;
        }
    }
#undef ATTN_LOAD
#undef ATTN_WRITE
}

// ---- Kernel 4: 5x5 dynamic stencil; 16 ch x 8-row stripe; 2 rows/thread ----
__global__ __launch_bounds__(256, 3) void out_k(const float* __restrict__ x,
                                                const float* __restrict__ dyn,
                                                float* __restrict__ out) {
    __shared__ float xt[16][12][60];
    int blk    = blockIdx.x;
    int stripe = blk % 7;
    int cg     = (blk / 7) % 24;
    int b      = blk / (7 * 24);
    int h0 = stripe * 8;
    int c0 = cg * 16;
    int t  = threadIdx.x;
    const float* xb = x + ((size_t)(b * CCH + c0)) * HW;

    if (t < 192) {
        int cc = t / 12, r = t % 12;
        xt[cc][r][0] = 0.f; xt[cc][r][1] = 0.f;
        xt[cc][r][58] = 0.f; xt[cc][r][59] = 0.f;
    }
#pragma unroll
    for (int k = 0; k < 11; k++) {
        int idx = t + 256 * k;
        if (k < 10 || t < 128) {
            int cc  = idx / 168;
            int rem = idx - cc * 168;
            int r   = rem / 14;
            int q   = rem - r * 14;
            int h   = h0 - 2 + r;
            float4 v = make_float4(0.f, 0.f, 0.f, 0.f);
            if ((unsigned)h < (unsigned)HH)
                v = *(const float4*)&xb[(size_t)cc * HW + h * WWD + 4 * q];
            xt[cc][r][2 + 4 * q + 0] = v.x;
            xt[cc][r][2 + 4 * q + 1] = v.y;
            xt[cc][r][2 + 4 * q + 2] = v.z;
            xt[cc][r][2 + 4 * q + 3] = v.w;
        }
    }

    bool act = t < 224;
    int w = t % 56;
    int u = t / 56;                  // 0..3 -> rows 2u, 2u+1
    int n = (h0 + 2 * u) * WWD + w;
    float dv0[K2], dv1[K2];
    if (act) {
        const float* db = dyn + (size_t)b * K2 * HW + n;
#pragma unroll
        for (int j = 0; j < K2; j++) {
            dv0[j] = db[(size_t)j * HW];
            dv1[j] = db[(size_t)j * HW + WWD];
        }
    }
    __syncthreads();
    if (!act) return;

    float* ob = out + ((size_t)(b * CCH + c0)) * HW + n;
#pragma unroll
    for (int cc = 0; cc < 16; cc++) {
        float a0 = 0.f, a1 = 0.f;
#pragma unroll
        for (int rr = 0; rr < 6; rr++) {
            int lr = 2 * u + rr;
            float v0 = xt[cc][lr][w + 0];
            float v1 = xt[cc][lr][w + 1];
            float v2 = xt[cc][lr][w + 2];
            float v3 = xt[cc][lr][w + 3];
            float v4 = xt[cc][lr][w + 4];
            if (rr < 5) {
                int o5 = rr * 5;
                a0 += v0 * dv0[o5] + v1 * dv0[o5 + 1] + v2 * dv0[o5 + 2]
                    + v3 * dv0[o5 + 3] + v4 * dv0[o5 + 4];
            }
            if (rr >= 1) {
                int o5 = (rr - 1) * 5;
                a1 += v0 * dv1[o5] + v1 * dv1[o5 + 1] + v2 * dv1[o5 + 2]
                    + v3 * dv1[o5 + 3] + v4 * dv1[o5 + 4];
            }
        }
        ob[(size_t)cc * HW] = a0;
        ob[(size_t)cc * HW + WWD] = a1;
    }
}

extern "C" void kernel_launch(void* const* d_in, const int* in_sizes, int n_in,
                              void* d_out, int out_size, void* d_ws, size_t ws_size,
                              hipStream_t stream) {
    const float* x   = (const float*)d_in[0];
    const float* ctx = (const float*)d_in[1];
    const float* Wq  = (const float*)d_in[2];
    const float* Wk  = (const float*)d_in[3];
    const float* Wwd = (const float*)d_in[4];
    float* out = (float*)d_out;
    float* ws  = (float*)d_ws;

    float* GT  = ws;                    // 384*384            = 147456  (GT transposed)
    float* M   = ws + 147456;           // B*384*52           =  79872
    float* dyn = ws + 147456 + 79872;   // B*25*3136          = 313600
    float* P   = dyn;                   // 196*384 = 75264, dead before attn_k writes dyn

    // NOTE swapped args: produces GTt[t][i] = sum_d Wq[d][t] Wk[d][i]
    gt_k<<<24 * 24, 256, 0, stream>>>(Wq, Wk, GT);
    pool_k<<<BB * S2, 384, 0, stream>>>(ctx, P);
    mv2_k<<<CCH / 2, 256, 0, stream>>>(GT, P, M);
    attn_k<<<BB * 196, 256, 0, stream>>>(x, M, Wwd, dyn);
    out_k<<<BB * 24 * 7, 256, 0, stream>>>(x, dyn, out);
}

// Round 6
// 163.308 us; speedup vs baseline: 1.0770x; 1.0319x over previous
//
#include <hip/hip_runtime.h>

#define BB 4
#define CCH 384
#define HH 56
#define WWD 56
#define HW 3136
#define S2 49
#define S2P 52
#define D2 192
#define K2 25
#define XSP 20          // xs leading dim

// ---- Kernel 1 (fused): blocks 0..575 -> GTt GEMM; blocks 576..771 -> pool.
// GTt[i][j] = sum_d Wa[d][i] * Wb[d][j]  (called with Wa=Wq, Wb=Wk).
// Pool: P[bs][c] = avg64(ctx bin).  The two are data-independent; fusing
// removes one launch gap and hides pool's streaming under the GEMM.
__global__ __launch_bounds__(256) void gtpool_k(const float* __restrict__ Wa,
                                                const float* __restrict__ Wb,
                                                const float* __restrict__ ctx,
                                                float* __restrict__ GT,
                                                float* __restrict__ P) {
    __shared__ float As[D2 * 16];
    __shared__ float Bs[D2 * 16];
    int blk = blockIdx.x;
    int t = threadIdx.x;
    if (blk < 576) {
        int bi = blk % 24, bj = blk / 24;
        int tj = t & 15, ti = t >> 4;
#pragma unroll
        for (int k = 0; k < 3; k++) {
            int idx = t + 256 * k;
            int d = idx >> 2, q = idx & 3;
            *(float4*)&As[idx * 4] = *(const float4*)&Wa[(size_t)d * CCH + bi * 16 + 4 * q];
            *(float4*)&Bs[idx * 4] = *(const float4*)&Wb[(size_t)d * CCH + bj * 16 + 4 * q];
        }
        __syncthreads();
        float acc = 0.f;
#pragma unroll 8
        for (int d = 0; d < D2; d++)
            acc += As[d * 16 + ti] * Bs[d * 16 + tj];
        GT[(size_t)(bi * 16 + ti) * CCH + bj * 16 + tj] = acc;
    } else {
        int bs = blk - 576;              // b*49 + s
        int b = bs / S2, s = bs - b * S2;
        int sy = s / 7, sx = s % 7;
        {
            const float* p = ctx + ((size_t)(b * CCH + t)) * HW + sy * 8 * WWD + sx * 8;
            float sum = 0.f;
#pragma unroll
            for (int r = 0; r < 8; r++) {
                float4 a  = *(const float4*)(p + r * WWD);
                float4 c4 = *(const float4*)(p + r * WWD + 4);
                sum += a.x + a.y + a.z + a.w + c4.x + c4.y + c4.z + c4.w;
            }
            P[(size_t)bs * CCH + t] = sum * (1.f / 64.f);
        }
        if (t < 128) {
            int c = t + 256;
            const float* p = ctx + ((size_t)(b * CCH + c)) * HW + sy * 8 * WWD + sx * 8;
            float sum = 0.f;
#pragma unroll
            for (int r = 0; r < 8; r++) {
                float4 a  = *(const float4*)(p + r * WWD);
                float4 c4 = *(const float4*)(p + r * WWD + 4);
                sum += a.x + a.y + a.z + a.w + c4.x + c4.y + c4.z + c4.w;
            }
            P[(size_t)bs * CCH + c] = sum * (1.f / 64.f);
        }
    }
}

// ---- Kernel 2: M[b,t,s] = GT row t . P[b*49+s]. 192 blocks x 256 thr.
// Each GT row is read by exactly ONE block; within a wave all lanes read the
// same GT float4 (L1 broadcast). P (301 KB) is L2-resident. ----
__global__ __launch_bounds__(256) void mv2_k(const float* __restrict__ GTt,
                                             const float* __restrict__ P,
                                             float* __restrict__ M) {
    int t = threadIdx.x;
    int r = blockIdx.x * 2 + (t >> 7);   // GT row / output channel
    int c = t & 127;
    int bs0 = c, bs1 = c + 128;
    bool has1 = (bs1 < BB * S2);         // 196 columns
    const float4* g4 = (const float4*)(GTt + (size_t)r * CCH);
    const float4* p0 = (const float4*)(P + (size_t)bs0 * CCH);
    const float4* p1 = (const float4*)(P + (size_t)(has1 ? bs1 : bs0) * CCH);
    float a0 = 0.f, a1 = 0.f, a2 = 0.f, a3 = 0.f;
#pragma unroll 8
    for (int i = 0; i < CCH / 4; i++) {
        float4 g  = g4[i];
        float4 q0 = p0[i];
        float4 q1 = p1[i];
        a0 += g.x * q0.x + g.y * q0.y;
        a1 += g.z * q0.z + g.w * q0.w;
        a2 += g.x * q1.x + g.y * q1.y;
        a3 += g.z * q1.z + g.w * q1.w;
    }
    int b0 = bs0 / S2, s0 = bs0 - b0 * S2;
    M[((size_t)(b0 * CCH + r)) * S2P + s0] = a0 + a1;
    if (has1) {
        int b1 = bs1 / S2, s1 = bs1 - b1 * S2;
        M[((size_t)(b1 * CCH + r)) * S2P + s1] = a2 + a3;
    }
    if (c >= 68 && c < 80) {             // zero the 3-col pad for each batch
        int rem = c - 68;                // 0..11
        int bb = rem / 3, sp = 49 + rem % 3;
        M[((size_t)(bb * CCH + r)) * S2P + sp] = 0.f;
    }
}

// ---- Kernel 3: scores = x^T M (16-way K-split), softmax(49), dyn = Wwd*A ----
// (unchanged)
__global__ __launch_bounds__(256) void attn_k(const float* __restrict__ x,
                                              const float* __restrict__ M,
                                              const float* __restrict__ Wwd,
                                              float* __restrict__ dyn) {
    __shared__ __align__(16) float smem[96 * XSP + 96 * S2P];  // xs | Ms ; red aliases
    __shared__ __align__(16) float sc[16 * S2P];
    __shared__ __align__(16) float wl[K2 * S2P];
    float* xs  = smem;               // [96][20]
    float* Ms  = smem + 96 * XSP;    // [96][52]
    float* red = smem;               // [4][16][52] = 3328 floats, aliases xs+Ms head

    int b  = blockIdx.x / 196;
    int n0 = (blockIdx.x % 196) * 16;
    int t  = threadIdx.x;
    int pxg = t & 3, sg = (t >> 2) & 3, slice = t >> 4;

    float4 acc4[4][4];
#pragma unroll
    for (int k = 0; k < 4; k++)
#pragma unroll
        for (int j = 0; j < 4; j++) acc4[k][j] = make_float4(0.f, 0.f, 0.f, 0.f);

    const float* xb = x + (size_t)b * CCH * HW + n0;
    const float* Mb = M + (size_t)b * CCH * S2P;

    // hoisted Wwd staging
#pragma unroll
    for (int k = 0; k < 5; k++) {
        int i = t + 256 * k;
        int j = i / S2P, ss = i - j * S2P;
        wl[i] = (ss < S2) ? Wwd[j * S2 + ss] : 0.f;
    }
    if (t < 20) {
        int i = t + 1280;
        int j = i / S2P, ss = i - j * S2P;
        wl[i] = (ss < S2) ? Wwd[j * S2 + ss] : 0.f;
    }

    int r0 = t >> 2, cq = t & 3;
    int r1 = (t + 256) >> 2;            // (t+256)&3 == t&3
    float4 px0, px1, pm0, pm1, pm2, pm3, pm4;

#define ATTN_LOAD(c0)                                                          \
    {                                                                          \
        px0 = *(const float4*)&xb[(size_t)((c0) + r0) * HW + 4 * cq];          \
        if (t < 128)                                                           \
            px1 = *(const float4*)&xb[(size_t)((c0) + r1) * HW + 4 * cq];      \
        const float* srcm = Mb + (size_t)(c0) * S2P;                           \
        pm0 = *(const float4*)&srcm[4 * t];                                    \
        pm1 = *(const float4*)&srcm[4 * (t + 256)];                            \
        pm2 = *(const float4*)&srcm[4 * (t + 512)];                            \
        pm3 = *(const float4*)&srcm[4 * (t + 768)];                            \
        if (t < 224) pm4 = *(const float4*)&srcm[4 * (t + 1024)];              \
    }

#define ATTN_WRITE()                                                           \
    {                                                                          \
        *(float4*)&xs[r0 * XSP + 4 * cq] = px0;                                \
        if (t < 128) *(float4*)&xs[r1 * XSP + 4 * cq] = px1;                   \
        *(float4*)&Ms[4 * t] = pm0;                                            \
        *(float4*)&Ms[4 * (t + 256)] = pm1;                                    \
        *(float4*)&Ms[4 * (t + 512)] = pm2;                                    \
        *(float4*)&Ms[4 * (t + 768)] = pm3;                                    \
        if (t < 224) *(float4*)&Ms[4 * (t + 1024)] = pm4;                      \
    }

    ATTN_LOAD(0);
    for (int ch = 0; ch < 4; ch++) {
        ATTN_WRITE();
        __syncthreads();
        if (ch < 3) { ATTN_LOAD((ch + 1) * 96); }
        int rbase = 6 * slice;
#pragma unroll
        for (int m = 0; m < 6; m++) {
            int r = rbase + m;
            const float4 xv = *(const float4*)&xs[r * XSP + 4 * pxg];
#pragma unroll
            for (int k = 0; k < 3; k++) {
                int g = sg + 4 * k;
                const float4 mv = *(const float4*)&Ms[r * S2P + 4 * g];
                acc4[k][0].x += mv.x * xv.x; acc4[k][0].y += mv.x * xv.y;
                acc4[k][0].z += mv.x * xv.z; acc4[k][0].w += mv.x * xv.w;
                acc4[k][1].x += mv.y * xv.x; acc4[k][1].y += mv.y * xv.y;
                acc4[k][1].z += mv.y * xv.z; acc4[k][1].w += mv.y * xv.w;
                acc4[k][2].x += mv.z * xv.x; acc4[k][2].y += mv.z * xv.y;
                acc4[k][2].z += mv.z * xv.z; acc4[k][2].w += mv.z * xv.w;
                acc4[k][3].x += mv.w * xv.x; acc4[k][3].y += mv.w * xv.y;
                acc4[k][3].z += mv.w * xv.z; acc4[k][3].w += mv.w * xv.w;
            }
            if (sg == 0) {
                const float4 mv = *(const float4*)&Ms[r * S2P + 48];
                acc4[3][0].x += mv.x * xv.x; acc4[3][0].y += mv.x * xv.y;
                acc4[3][0].z += mv.x * xv.z; acc4[3][0].w += mv.x * xv.w;
                acc4[3][1].x += mv.y * xv.x; acc4[3][1].y += mv.y * xv.y;
                acc4[3][1].z += mv.y * xv.z; acc4[3][1].w += mv.y * xv.w;
                acc4[3][2].x += mv.z * xv.x; acc4[3][2].y += mv.z * xv.y;
                acc4[3][2].z += mv.z * xv.z; acc4[3][2].w += mv.z * xv.w;
                acc4[3][3].x += mv.w * xv.x; acc4[3][3].y += mv.w * xv.y;
                acc4[3][3].z += mv.w * xv.z; acc4[3][3].w += mv.w * xv.w;
            }
        }
        __syncthreads();
    }

    // in-wave reduce across 4 slice-groups (lane^16, lane^32)
#pragma unroll
    for (int k = 0; k < 4; k++)
#pragma unroll
        for (int j = 0; j < 4; j++) {
            acc4[k][j].x += __shfl_xor(acc4[k][j].x, 16);
            acc4[k][j].y += __shfl_xor(acc4[k][j].y, 16);
            acc4[k][j].z += __shfl_xor(acc4[k][j].z, 16);
            acc4[k][j].w += __shfl_xor(acc4[k][j].w, 16);
            acc4[k][j].x += __shfl_xor(acc4[k][j].x, 32);
            acc4[k][j].y += __shfl_xor(acc4[k][j].y, 32);
            acc4[k][j].z += __shfl_xor(acc4[k][j].z, 32);
            acc4[k][j].w += __shfl_xor(acc4[k][j].w, 32);
        }

    // wave partials -> red[wave][16px][52]
    if ((t & 63) < 16) {
        int wv = t >> 6;
        float* rb = red + (size_t)wv * 16 * S2P;
#pragma unroll
        for (int k = 0; k < 4; k++) {
            int g = sg + 4 * k;
            if (g < 13) {
                *(float4*)&rb[(4 * pxg + 0) * S2P + 4 * g] =
                    make_float4(acc4[k][0].x, acc4[k][1].x, acc4[k][2].x, acc4[k][3].x);
                *(float4*)&rb[(4 * pxg + 1) * S2P + 4 * g] =
                    make_float4(acc4[k][0].y, acc4[k][1].y, acc4[k][2].y, acc4[k][3].y);
                *(float4*)&rb[(4 * pxg + 2) * S2P + 4 * g] =
                    make_float4(acc4[k][0].z, acc4[k][1].z, acc4[k][2].z, acc4[k][3].z);
                *(float4*)&rb[(4 * pxg + 3) * S2P + 4 * g] =
                    make_float4(acc4[k][0].w, acc4[k][1].w, acc4[k][2].w, acc4[k][3].w);
            }
        }
    }
    __syncthreads();

    // final reduce over 4 waves -> sc
    if (t < 208) {
        int px = t / 13, q = t - px * 13;
        float4 ssum = make_float4(0.f, 0.f, 0.f, 0.f);
#pragma unroll
        for (int wv = 0; wv < 4; wv++) {
            float4 vv = *(float4*)&red[(size_t)(wv * 16 + px) * S2P + 4 * q];
            ssum.x += vv.x; ssum.y += vv.y; ssum.z += vv.z; ssum.w += vv.w;
        }
        *(float4*)&sc[px * S2P + 4 * q] = ssum;
    }
    __syncthreads();

    // softmax (threads < 128: 8 lanes per pixel); wl already staged
    if (t < 128) {
        int px = t >> 3, li = t & 7;
        float mx = -3.4e38f;
#pragma unroll
        for (int k = 0; k < 7; k++) { int s = li + 8 * k; if (s < S2) mx = fmaxf(mx, sc[px * S2P + s]); }
        mx = fmaxf(mx, __shfl_xor(mx, 1, 8));
        mx = fmaxf(mx, __shfl_xor(mx, 2, 8));
        mx = fmaxf(mx, __shfl_xor(mx, 4, 8));
        float e[7]; float sum = 0.f;
#pragma unroll
        for (int k = 0; k < 7; k++) {
            int s = li + 8 * k;
            if (s < S2) { e[k] = __expf(sc[px * S2P + s] - mx); sum += e[k]; }
        }
        sum += __shfl_xor(sum, 1, 8);
        sum += __shfl_xor(sum, 2, 8);
        sum += __shfl_xor(sum, 4, 8);
        float inv = 1.f / sum;
#pragma unroll
        for (int k = 0; k < 7; k++) {
            int s = li + 8 * k;
            if (s < S2) sc[px * S2P + s] = e[k] * inv;
        }
    }
    __syncthreads();

    // dyn[b,j,n0+px] = sum_s wl[j,s]*sc[px,s]   (400 outs: 256 + 144)
    float* dynb = dyn + (size_t)b * K2 * HW + n0;
#pragma unroll
    for (int pass = 0; pass < 2; pass++) {
        int o = t + 256 * pass;
        if (pass == 0 || t < 144) {
            int j = o >> 4, px = o & 15;
            float a = 0.f;
#pragma unroll
            for (int q = 0; q < 13; q++) {
                float4 wv = *(float4*)&wl[j * S2P + 4 * q];
                float4 pv = *(float4*)&sc[px * S2P + 4 * q];
                a += wv.x * pv.x + wv.y * pv.y + wv.z * pv.z + wv.w * pv.w;
            }
            dynb[(size_t)j * HW + px] = a;
        }
    }
#undef ATTN_LOAD
#undef ATTN_WRITE
}

// ---- Kernel 4: 5x5 dynamic stencil; 16 ch x 8-row stripe; 2 rows/thread ----
__global__ __launch_bounds__(256, 3) void out_k(const float* __restrict__ x,
                                                const float* __restrict__ dyn,
                                                float* __restrict__ out) {
    __shared__ float xt[16][12][60];
    int blk    = blockIdx.x;
    int stripe = blk % 7;
    int cg     = (blk / 7) % 24;
    int b      = blk / (7 * 24);
    int h0 = stripe * 8;
    int c0 = cg * 16;
    int t  = threadIdx.x;
    const float* xb = x + ((size_t)(b * CCH + c0)) * HW;

    if (t < 192) {
        int cc = t / 12, r = t % 12;
        xt[cc][r][0] = 0.f; xt[cc][r][1] = 0.f;
        xt[cc][r][58] = 0.f; xt[cc][r][59] = 0.f;
    }
#pragma unroll
    for (int k = 0; k < 11; k++) {
        int idx = t + 256 * k;
        if (k < 10 || t < 128) {
            int cc  = idx / 168;
            int rem = idx - cc * 168;
            int r   = rem / 14;
            int q   = rem - r * 14;
            int h   = h0 - 2 + r;
            float4 v = make_float4(0.f, 0.f, 0.f, 0.f);
            if ((unsigned)h < (unsigned)HH)
                v = *(const float4*)&xb[(size_t)cc * HW + h * WWD + 4 * q];
            xt[cc][r][2 + 4 * q + 0] = v.x;
            xt[cc][r][2 + 4 * q + 1] = v.y;
            xt[cc][r][2 + 4 * q + 2] = v.z;
            xt[cc][r][2 + 4 * q + 3] = v.w;
        }
    }

    bool act = t < 224;
    int w = t % 56;
    int u = t / 56;                  // 0..3 -> rows 2u, 2u+1
    int n = (h0 + 2 * u) * WWD + w;
    float dv0[K2], dv1[K2];
    if (act) {
        const float* db = dyn + (size_t)b * K2 * HW + n;
#pragma unroll
        for (int j = 0; j < K2; j++) {
            dv0[j] = db[(size_t)j * HW];
            dv1[j] = db[(size_t)j * HW + WWD];
        }
    }
    __syncthreads();
    if (!act) return;

    float* ob = out + ((size_t)(b * CCH + c0)) * HW + n;
#pragma unroll
    for (int cc = 0; cc < 16; cc++) {
        float a0 = 0.f, a1 = 0.f;
#pragma unroll
        for (int rr = 0; rr < 6; rr++) {
            int lr = 2 * u + rr;
            float v0 = xt[cc][lr][w + 0];
            float v1 = xt[cc][lr][w + 1];
            float v2 = xt[cc][lr][w + 2];
            float v3 = xt[cc][lr][w + 3];
            float v4 = xt[cc][lr][w + 4];
            if (rr < 5) {
                int o5 = rr * 5;
                a0 += v0 * dv0[o5] + v1 * dv0[o5 + 1] + v2 * dv0[o5 + 2]
                    + v3 * dv0[o5 + 3] + v4 * dv0[o5 + 4];
            }
            if (rr >= 1) {
                int o5 = (rr - 1) * 5;
                a1 += v0 * dv1[o5] + v1 * dv1[o5 + 1] + v2 * dv1[o5 + 2]
                    + v3 * dv1[o5 + 3] + v4 * dv1[o5 + 4];
            }
        }
        ob[(size_t)cc * HW] = a0;
        ob[(size_t)cc * HW + WWD] = a1;
    }
}

extern "C" void kernel_launch(void* const* d_in, const int* in_sizes, int n_in,
                              void* d_out, int out_size, void* d_ws, size_t ws_size,
                              hipStream_t stream) {
    const float* x   = (const float*)d_in[0];
    const float* ctx = (const float*)d_in[1];
    const float* Wq  = (const float*)d_in[2];
    const float* Wk  = (const float*)d_in[3];
    const float* Wwd = (const float*)d_in[4];
    float* out = (float*)d_out;
    float* ws  = (float*)d_ws;

    float* GT  = ws;                    // 384*384            = 147456  (GT transposed)
    float* M   = ws + 147456;           // B*384*52           =  79872
    float* dyn = ws + 147456 + 79872;   // B*25*3136          = 313600
    float* P   = dyn;                   // 196*384 = 75264, dead before attn_k writes dyn

    // fused: blocks 0..575 compute GTt[i][j] = sum_d Wq[d][i] Wk[d][j];
    // blocks 576..771 pool ctx -> P
    gtpool_k<<<576 + 196, 256, 0, stream>>>(Wq, Wk, ctx, GT, P);
    mv2_k<<<CCH / 2, 256, 0, stream>>>(GT, P, M);
    attn_k<<<BB * 196, 256, 0, stream>>>(x, M, Wwd, dyn);
    out_k<<<BB * 24 * 7, 256, 0, stream>>>(x, dyn, out);
}

// Round 7
// 149.360 us; speedup vs baseline: 1.1775x; 1.0934x over previous
//
#include <hip/hip_runtime.h>

#define BB 4
#define CCH 384
#define HH 56
#define WWD 56
#define HW 3136
#define S2 49
#define S2P 52
#define D2 192
#define K2 25
#define XSP 20          // xs leading dim
#define NBS 196         // BB*S2

// ---- Kernel 1 (fused): blocks 0..575 -> GTt GEMM; blocks 576..911 -> pool.
// GTt[i][j] = sum_d Wa[d][i] * Wb[d][j]  (called with Wa=Wq, Wb=Wk).
// Pool v2 (coalesced): block = (b, sy, 32-channel group). Each channel's
// 8x56 slab is 448 CONTIGUOUS floats; waves read 1KB contiguous segments.
// Output transposed: PT[c][bs] so mv2's lane reads are coalesced.
__global__ __launch_bounds__(256) void gtpool_k(const float* __restrict__ Wa,
                                                const float* __restrict__ Wb,
                                                const float* __restrict__ ctx,
                                                float* __restrict__ GT,
                                                float* __restrict__ PT) {
    __shared__ float sh[6144];           // GEMM: As|Bs (3072+3072). Pool: part[3584]
    int blk = blockIdx.x;
    int t = threadIdx.x;
    if (blk < 576) {
        float* As = sh;
        float* Bs = sh + 3072;
        int bi = blk % 24, bj = blk / 24;
        int tj = t & 15, ti = t >> 4;
#pragma unroll
        for (int k = 0; k < 3; k++) {
            int idx = t + 256 * k;
            int d = idx >> 2, q = idx & 3;
            *(float4*)&As[idx * 4] = *(const float4*)&Wa[(size_t)d * CCH + bi * 16 + 4 * q];
            *(float4*)&Bs[idx * 4] = *(const float4*)&Wb[(size_t)d * CCH + bj * 16 + 4 * q];
        }
        __syncthreads();
        float acc = 0.f;
#pragma unroll 8
        for (int d = 0; d < D2; d++)
            acc += As[d * 16 + ti] * Bs[d * 16 + tj];
        GT[(size_t)(bi * 16 + ti) * CCH + bj * 16 + tj] = acc;
    } else {
        float* part = sh;                // [32][8][14]
        int pb = blk - 576;              // b*84 + sy*12 + cg
        int b  = pb / 84;
        int rem = pb - b * 84;
        int sy = rem / 12;
        int cg = rem - sy * 12;
        int c0 = cg * 32;
        const float* base = ctx + ((size_t)(b * CCH + c0)) * HW + sy * 8 * WWD;
        // 32 channels x 448 contiguous floats = 3584 float4 reads, coalesced
#pragma unroll
        for (int k = 0; k < 14; k++) {
            int g = t + 256 * k;         // [0, 3584)
            int cc = g / 112;
            int r2 = g - cc * 112;       // float4 index within 448-float slab
            float4 v = *(const float4*)(base + (size_t)cc * HW + 4 * r2);
            part[g] = (v.x + v.y) + (v.z + v.w);
        }
        __syncthreads();
        // reduce 16 partials per (cc, sx) bin: rows r=0..7, jj = 2sx, 2sx+1
        if (t < 224) {
            int cc = t / 7, sx = t - cc * 7;
            float sum = 0.f;
#pragma unroll
            for (int r = 0; r < 8; r++) {
                sum += part[cc * 112 + r * 14 + 2 * sx]
                     + part[cc * 112 + r * 14 + 2 * sx + 1];
            }
            int bs = b * S2 + sy * 7 + sx;
            PT[(size_t)(c0 + cc) * NBS + bs] = sum * (1.f / 64.f);
        }
    }
}

// ---- Kernel 2: M[b,t,s] = GT row t . PT[:, bs]. 192 blocks x 256 thr.
// GT row load is wave-uniform (1 broadcast transaction); PT row reads are
// lane-consecutive (coalesced 256B). Two rows per block (t>>7).
__global__ __launch_bounds__(256) void mv2_k(const float* __restrict__ GTt,
                                             const float* __restrict__ PT,
                                             float* __restrict__ M) {
    int t = threadIdx.x;
    int r = blockIdx.x * 2 + (t >> 7);   // GT row / output channel
    int c = t & 127;                     // bs0 = c; bs1 = c + 128
    bool has1 = (c < NBS - 128);         // c < 68
    int c1 = has1 ? c + 128 : c;
    const float* g = GTt + (size_t)r * CCH;
    float a0 = 0.f, a1 = 0.f;
#pragma unroll 8
    for (int i = 0; i < CCH; i++) {
        float gv = g[i];
        a0 += gv * PT[(size_t)i * NBS + c];
        a1 += gv * PT[(size_t)i * NBS + c1];
    }
    int b0 = c / S2, s0 = c - b0 * S2;
    M[((size_t)(b0 * CCH + r)) * S2P + s0] = a0;
    if (has1) {
        int bs1 = c + 128;
        int b1 = bs1 / S2, s1 = bs1 - b1 * S2;
        M[((size_t)(b1 * CCH + r)) * S2P + s1] = a1;
    }
    if (c >= 68 && c < 80) {             // zero the 3-col pad for each batch
        int rem = c - 68;                // 0..11
        int bb = rem / 3, sp = 49 + rem % 3;
        M[((size_t)(bb * CCH + r)) * S2P + sp] = 0.f;
    }
}

// ---- Kernel 3: scores = x^T M (16-way K-split), softmax(49), dyn = Wwd*A ----
// (unchanged)
__global__ __launch_bounds__(256) void attn_k(const float* __restrict__ x,
                                              const float* __restrict__ M,
                                              const float* __restrict__ Wwd,
                                              float* __restrict__ dyn) {
    __shared__ __align__(16) float smem[96 * XSP + 96 * S2P];  // xs | Ms ; red aliases
    __shared__ __align__(16) float sc[16 * S2P];
    __shared__ __align__(16) float wl[K2 * S2P];
    float* xs  = smem;               // [96][20]
    float* Ms  = smem + 96 * XSP;    // [96][52]
    float* red = smem;               // [4][16][52] = 3328 floats, aliases xs+Ms head

    int b  = blockIdx.x / 196;
    int n0 = (blockIdx.x % 196) * 16;
    int t  = threadIdx.x;
    int pxg = t & 3, sg = (t >> 2) & 3, slice = t >> 4;

    float4 acc4[4][4];
#pragma unroll
    for (int k = 0; k < 4; k++)
#pragma unroll
        for (int j = 0; j < 4; j++) acc4[k][j] = make_float4(0.f, 0.f, 0.f, 0.f);

    const float* xb = x + (size_t)b * CCH * HW + n0;
    const float* Mb = M + (size_t)b * CCH * S2P;

    // hoisted Wwd staging
#pragma unroll
    for (int k = 0; k < 5; k++) {
        int i = t + 256 * k;
        int j = i / S2P, ss = i - j * S2P;
        wl[i] = (ss < S2) ? Wwd[j * S2 + ss] : 0.f;
    }
    if (t < 20) {
        int i = t + 1280;
        int j = i / S2P, ss = i - j * S2P;
        wl[i] = (ss < S2) ? Wwd[j * S2 + ss] : 0.f;
    }

    int r0 = t >> 2, cq = t & 3;
    int r1 = (t + 256) >> 2;            // (t+256)&3 == t&3
    float4 px0, px1, pm0, pm1, pm2, pm3, pm4;

#define ATTN_LOAD(c0)                                                          \
    {                                                                          \
        px0 = *(const float4*)&xb[(size_t)((c0) + r0) * HW + 4 * cq];          \
        if (t < 128)                                                           \
            px1 = *(const float4*)&xb[(size_t)((c0) + r1) * HW + 4 * cq];      \
        const float* srcm = Mb + (size_t)(c0) * S2P;                           \
        pm0 = *(const float4*)&srcm[4 * t];                                    \
        pm1 = *(const float4*)&srcm[4 * (t + 256)];                            \
        pm2 = *(const float4*)&srcm[4 * (t + 512)];                            \
        pm3 = *(const float4*)&srcm[4 * (t + 768)];                            \
        if (t < 224) pm4 = *(const float4*)&srcm[4 * (t + 1024)];              \
    }

#define ATTN_WRITE()                                                           \
    {                                                                          \
        *(float4*)&xs[r0 * XSP + 4 * cq] = px0;                                \
        if (t < 128) *(float4*)&xs[r1 * XSP + 4 * cq] = px1;                   \
        *(float4*)&Ms[4 * t] = pm0;                                            \
        *(float4*)&Ms[4 * (t + 256)] = pm1;                                    \
        *(float4*)&Ms[4 * (t + 512)] = pm2;                                    \
        *(float4*)&Ms[4 * (t + 768)] = pm3;                                    \
        if (t < 224) *(float4*)&Ms[4 * (t + 1024)] = pm4;                      \
    }

    ATTN_LOAD(0);
    for (int ch = 0; ch < 4; ch++) {
        ATTN_WRITE();
        __syncthreads();
        if (ch < 3) { ATTN_LOAD((ch + 1) * 96); }
        int rbase = 6 * slice;
#pragma unroll
        for (int m = 0; m < 6; m++) {
            int r = rbase + m;
            const float4 xv = *(const float4*)&xs[r * XSP + 4 * pxg];
#pragma unroll
            for (int k = 0; k < 3; k++) {
                int g = sg + 4 * k;
                const float4 mv = *(const float4*)&Ms[r * S2P + 4 * g];
                acc4[k][0].x += mv.x * xv.x; acc4[k][0].y += mv.x * xv.y;
                acc4[k][0].z += mv.x * xv.z; acc4[k][0].w += mv.x * xv.w;
                acc4[k][1].x += mv.y * xv.x; acc4[k][1].y += mv.y * xv.y;
                acc4[k][1].z += mv.y * xv.z; acc4[k][1].w += mv.y * xv.w;
                acc4[k][2].x += mv.z * xv.x; acc4[k][2].y += mv.z * xv.y;
                acc4[k][2].z += mv.z * xv.z; acc4[k][2].w += mv.z * xv.w;
                acc4[k][3].x += mv.w * xv.x; acc4[k][3].y += mv.w * xv.y;
                acc4[k][3].z += mv.w * xv.z; acc4[k][3].w += mv.w * xv.w;
            }
            if (sg == 0) {
                const float4 mv = *(const float4*)&Ms[r * S2P + 48];
                acc4[3][0].x += mv.x * xv.x; acc4[3][0].y += mv.x * xv.y;
                acc4[3][0].z += mv.x * xv.z; acc4[3][0].w += mv.x * xv.w;
                acc4[3][1].x += mv.y * xv.x; acc4[3][1].y += mv.y * xv.y;
                acc4[3][1].z += mv.y * xv.z; acc4[3][1].w += mv.y * xv.w;
                acc4[3][2].x += mv.z * xv.x; acc4[3][2].y += mv.z * xv.y;
                acc4[3][2].z += mv.z * xv.z; acc4[3][2].w += mv.z * xv.w;
                acc4[3][3].x += mv.w * xv.x; acc4[3][3].y += mv.w * xv.y;
                acc4[3][3].z += mv.w * xv.z; acc4[3][3].w += mv.w * xv.w;
            }
        }
        __syncthreads();
    }

    // in-wave reduce across 4 slice-groups (lane^16, lane^32)
#pragma unroll
    for (int k = 0; k < 4; k++)
#pragma unroll
        for (int j = 0; j < 4; j++) {
            acc4[k][j].x += __shfl_xor(acc4[k][j].x, 16);
            acc4[k][j].y += __shfl_xor(acc4[k][j].y, 16);
            acc4[k][j].z += __shfl_xor(acc4[k][j].z, 16);
            acc4[k][j].w += __shfl_xor(acc4[k][j].w, 16);
            acc4[k][j].x += __shfl_xor(acc4[k][j].x, 32);
            acc4[k][j].y += __shfl_xor(acc4[k][j].y, 32);
            acc4[k][j].z += __shfl_xor(acc4[k][j].z, 32);
            acc4[k][j].w += __shfl_xor(acc4[k][j].w, 32);
        }

    // wave partials -> red[wave][16px][52]
    if ((t & 63) < 16) {
        int wv = t >> 6;
        float* rb = red + (size_t)wv * 16 * S2P;
#pragma unroll
        for (int k = 0; k < 4; k++) {
            int g = sg + 4 * k;
            if (g < 13) {
                *(float4*)&rb[(4 * pxg + 0) * S2P + 4 * g] =
                    make_float4(acc4[k][0].x, acc4[k][1].x, acc4[k][2].x, acc4[k][3].x);
                *(float4*)&rb[(4 * pxg + 1) * S2P + 4 * g] =
                    make_float4(acc4[k][0].y, acc4[k][1].y, acc4[k][2].y, acc4[k][3].y);
                *(float4*)&rb[(4 * pxg + 2) * S2P + 4 * g] =
                    make_float4(acc4[k][0].z, acc4[k][1].z, acc4[k][2].z, acc4[k][3].z);
                *(float4*)&rb[(4 * pxg + 3) * S2P + 4 * g] =
                    make_float4(acc4[k][0].w, acc4[k][1].w, acc4[k][2].w, acc4[k][3].w);
            }
        }
    }
    __syncthreads();

    // final reduce over 4 waves -> sc
    if (t < 208) {
        int px = t / 13, q = t - px * 13;
        float4 ssum = make_float4(0.f, 0.f, 0.f, 0.f);
#pragma unroll
        for (int wv = 0; wv < 4; wv++) {
            float4 vv = *(float4*)&red[(size_t)(wv * 16 + px) * S2P + 4 * q];
            ssum.x += vv.x; ssum.y += vv.y; ssum.z += vv.z; ssum.w += vv.w;
        }
        *(float4*)&sc[px * S2P + 4 * q] = ssum;
    }
    __syncthreads();

    // softmax (threads < 128: 8 lanes per pixel); wl already staged
    if (t < 128) {
        int px = t >> 3, li = t & 7;
        float mx = -3.4e38f;
#pragma unroll
        for (int k = 0; k < 7; k++) { int s = li + 8 * k; if (s < S2) mx = fmaxf(mx, sc[px * S2P + s]); }
        mx = fmaxf(mx, __shfl_xor(mx, 1, 8));
        mx = fmaxf(mx, __shfl_xor(mx, 2, 8));
        mx = fmaxf(mx, __shfl_xor(mx, 4, 8));
        float e[7]; float sum = 0.f;
#pragma unroll
        for (int k = 0; k < 7; k++) {
            int s = li + 8 * k;
            if (s < S2) { e[k] = __expf(sc[px * S2P + s] - mx); sum += e[k]; }
        }
        sum += __shfl_xor(sum, 1, 8);
        sum += __shfl_xor(sum, 2, 8);
        sum += __shfl_xor(sum, 4, 8);
        float inv = 1.f / sum;
#pragma unroll
        for (int k = 0; k < 7; k++) {
            int s = li + 8 * k;
            if (s < S2) sc[px * S2P + s] = e[k] * inv;
        }
    }
    __syncthreads();

    // dyn[b,j,n0+px] = sum_s wl[j,s]*sc[px,s]   (400 outs: 256 + 144)
    float* dynb = dyn + (size_t)b * K2 * HW + n0;
#pragma unroll
    for (int pass = 0; pass < 2; pass++) {
        int o = t + 256 * pass;
        if (pass == 0 || t < 144) {
            int j = o >> 4, px = o & 15;
            float a = 0.f;
#pragma unroll
            for (int q = 0; q < 13; q++) {
                float4 wv = *(float4*)&wl[j * S2P + 4 * q];
                float4 pv = *(float4*)&sc[px * S2P + 4 * q];
                a += wv.x * pv.x + wv.y * pv.y + wv.z * pv.z + wv.w * pv.w;
            }
            dynb[(size_t)j * HW + px] = a;
        }
    }
#undef ATTN_LOAD
#undef ATTN_WRITE
}

// ---- Kernel 4: 5x5 dynamic stencil; 16 ch x 8-row stripe; 2 rows/thread ----
__global__ __launch_bounds__(256, 3) void out_k(const float* __restrict__ x,
                                                const float* __restrict__ dyn,
                                                float* __restrict__ out) {
    __shared__ float xt[16][12][60];
    int blk    = blockIdx.x;
    int stripe = blk % 7;
    int cg     = (blk / 7) % 24;
    int b      = blk / (7 * 24);
    int h0 = stripe * 8;
    int c0 = cg * 16;
    int t  = threadIdx.x;
    const float* xb = x + ((size_t)(b * CCH + c0)) * HW;

    if (t < 192) {
        int cc = t / 12, r = t % 12;
        xt[cc][r][0] = 0.f; xt[cc][r][1] = 0.f;
        xt[cc][r][58] = 0.f; xt[cc][r][59] = 0.f;
    }
#pragma unroll
    for (int k = 0; k < 11; k++) {
        int idx = t + 256 * k;
        if (k < 10 || t < 128) {
            int cc  = idx / 168;
            int rem = idx - cc * 168;
            int r   = rem / 14;
            int q   = rem - r * 14;
            int h   = h0 - 2 + r;
            float4 v = make_float4(0.f, 0.f, 0.f, 0.f);
            if ((unsigned)h < (unsigned)HH)
                v = *(const float4*)&xb[(size_t)cc * HW + h * WWD + 4 * q];
            xt[cc][r][2 + 4 * q + 0] = v.x;
            xt[cc][r][2 + 4 * q + 1] = v.y;
            xt[cc][r][2 + 4 * q + 2] = v.z;
            xt[cc][r][2 + 4 * q + 3] = v.w;
        }
    }

    bool act = t < 224;
    int w = t % 56;
    int u = t / 56;                  // 0..3 -> rows 2u, 2u+1
    int n = (h0 + 2 * u) * WWD + w;
    float dv0[K2], dv1[K2];
    if (act) {
        const float* db = dyn + (size_t)b * K2 * HW + n;
#pragma unroll
        for (int j = 0; j < K2; j++) {
            dv0[j] = db[(size_t)j * HW];
            dv1[j] = db[(size_t)j * HW + WWD];
        }
    }
    __syncthreads();
    if (!act) return;

    float* ob = out + ((size_t)(b * CCH + c0)) * HW + n;
#pragma unroll
    for (int cc = 0; cc < 16; cc++) {
        float a0 = 0.f, a1 = 0.f;
#pragma unroll
        for (int rr = 0; rr < 6; rr++) {
            int lr = 2 * u + rr;
            float v0 = xt[cc][lr][w + 0];
            float v1 = xt[cc][lr][w + 1];
            float v2 = xt[cc][lr][w + 2];
            float v3 = xt[cc][lr][w + 3];
            float v4 = xt[cc][lr][w + 4];
            if (rr < 5) {
                int o5 = rr * 5;
                a0 += v0 * dv0[o5] + v1 * dv0[o5 + 1] + v2 * dv0[o5 + 2]
                    + v3 * dv0[o5 + 3] + v4 * dv0[o5 + 4];
            }
            if (rr >= 1) {
                int o5 = (rr - 1) * 5;
                a1 += v0 * dv1[o5] + v1 * dv1[o5 + 1] + v2 * dv1[o5 + 2]
                    + v3 * dv1[o5 + 3] + v4 * dv1[o5 + 4];
            }
        }
        ob[(size_t)cc * HW] = a0;
        ob[(size_t)cc * HW + WWD] = a1;
    }
}

extern "C" void kernel_launch(void* const* d_in, const int* in_sizes, int n_in,
                              void* d_out, int out_size, void* d_ws, size_t ws_size,
                              hipStream_t stream) {
    const float* x   = (const float*)d_in[0];
    const float* ctx = (const float*)d_in[1];
    const float* Wq  = (const float*)d_in[2];
    const float* Wk  = (const float*)d_in[3];
    const float* Wwd = (const float*)d_in[4];
    float* out = (float*)d_out;
    float* ws  = (float*)d_ws;

    float* GT  = ws;                    // 384*384            = 147456  (GT transposed)
    float* M   = ws + 147456;           // B*384*52           =  79872
    float* dyn = ws + 147456 + 79872;   // B*25*3136          = 313600
    float* PT  = dyn;                   // 384*196 = 75264, dead before attn_k writes dyn

    // fused: blocks 0..575 GTt GEMM; blocks 576..911 pool ctx -> PT (transposed)
    gtpool_k<<<576 + 336, 256, 0, stream>>>(Wq, Wk, ctx, GT, PT);
    mv2_k<<<CCH / 2, 256, 0, stream>>>(GT, PT, M);
    attn_k<<<BB * 196, 256, 0, stream>>>(x, M, Wwd, dyn);
    out_k<<<BB * 24 * 7, 256, 0, stream>>>(x, dyn, out);
}